// Round 7
// baseline (194.558 us; speedup 1.0000x reference)
//
#include <hip/hip_runtime.h>

// Full-coverage nt-load shape: 4 float4s per thread per stream = 8 nt
// dwordx4 loads in flight, single pass (no loop) at the bench shape.
// nt: misses don't allocate in L2/L3 -> no churn against the harness's
// restore working set; all reads stream from HBM at copy-engine rate.
constexpr int TPB  = 256;
constexpr int TPB2 = 1024;

typedef float f32x4 __attribute__((ext_vector_type(4)));

// Element 4q+k has component (q+k)%3; component 2 is the angle term:
//   (clamp_angle(2*pi*d)/pi)^2 == (2*min(f,1-f))^2, f = fract(|d|)
__device__ __forceinline__ float f4_contrib(f32x4 p, f32x4 l, int c) {
    constexpr int want[4] = {2, 1, 0, 2};   // slot k is angle iff c == want[k]
    float acc = 0.0f;
#pragma unroll
    for (int k = 0; k < 4; ++k) {
        float d = p[k] - l[k];
        float x = fabsf(d);
        float f = x - floorf(x);
        float t = 2.0f * fminf(f, 1.0f - f);
        float v = (c == want[k]) ? t : d;
        acc = fmaf(v, v, acc);
    }
    return acc;
}

__device__ __forceinline__ int mod3(long long q) { return (int)(q % 3); }

__global__ __launch_bounds__(TPB) void loss_partial_kernel(
    const float* __restrict__ pred,
    const float* __restrict__ lab,
    float* __restrict__ partial,
    long long n4,        // float4s per stream
    long long n_elems)   // floats per stream
{
    const long long tid = (long long)blockIdx.x * TPB + threadIdx.x;
    const long long S   = (long long)gridDim.x * TPB;   // 1572864; S % 3 == 0

    const f32x4* __restrict__ p4 = (const f32x4*)pred;
    const f32x4* __restrict__ l4 = (const f32x4*)lab;

    float acc = 0.0f;

    const long long iters = n4 / (4 * S);   // 1 at the bench shape
    long long q = tid;
    for (long long it = 0; it < iters; ++it) {
        // 8 nt dwordx4 loads, all independent.
        f32x4 pa = __builtin_nontemporal_load(p4 + q);
        f32x4 pb = __builtin_nontemporal_load(p4 + q + S);
        f32x4 pc = __builtin_nontemporal_load(p4 + q + 2 * S);
        f32x4 pd = __builtin_nontemporal_load(p4 + q + 3 * S);
        f32x4 la = __builtin_nontemporal_load(l4 + q);
        f32x4 lb = __builtin_nontemporal_load(l4 + q + S);
        f32x4 lc = __builtin_nontemporal_load(l4 + q + 2 * S);
        f32x4 ld = __builtin_nontemporal_load(l4 + q + 3 * S);

        const int c0 = mod3(q);           // S % 3 == 0 for the bench shape,
        const int c1 = mod3(q + S);       // but compute each phase anyway
        const int c2 = mod3(q + 2 * S);   // (once per thread, negligible).
        const int c3 = mod3(q + 3 * S);

        acc += f4_contrib(pa, la, c0);
        acc += f4_contrib(pb, lb, c1);
        acc += f4_contrib(pc, lc, c2);
        acc += f4_contrib(pd, ld, c3);

        q += 4 * S;
    }

    // Generic float4 remainder (empty at the bench shape).
    for (; q < n4; q += S) {
        f32x4 pv = __builtin_nontemporal_load(p4 + q);
        f32x4 lv = __builtin_nontemporal_load(l4 + q);
        acc += f4_contrib(pv, lv, mod3(q));
    }

    // Scalar element tail (empty when n_elems % 4 == 0).
    const long long tail_base = n4 * 4;
    if (tid < n_elems - tail_base) {
        long long e = tail_base + tid;
        float d = pred[e] - lab[e];
        if (mod3(e) == 2) {
            float x = fabsf(d);
            float f = x - floorf(x);
            d = 2.0f * fminf(f, 1.0f - f);
        }
        acc = fmaf(d, d, acc);
    }

    // Wave-64 butterfly reduce.
#pragma unroll
    for (int off = 32; off > 0; off >>= 1)
        acc += __shfl_down(acc, off, 64);

    __shared__ float s_partial[TPB / 64];
    const int lane = threadIdx.x & 63;
    const int wave = threadIdx.x >> 6;
    if (lane == 0) s_partial[wave] = acc;
    __syncthreads();

    if (threadIdx.x == 0) {
        float v = 0.0f;
#pragma unroll
        for (int w = 0; w < TPB / 64; ++w) v += s_partial[w];
        partial[blockIdx.x] = v;   // no atomics
    }
}

// Stage 2: one 1024-thread block reduces `n` partials -> out[0].
// Writes out directly (overwrites the 0xAA poison; no memset needed).
__global__ __launch_bounds__(TPB2) void reduce_partials_kernel(
    const float* __restrict__ partial, float* __restrict__ out, int n)
{
    float acc = 0.0f;
    const int n4p = n / 4;
    const float4* __restrict__ p4 = (const float4*)partial;
    for (int i = threadIdx.x; i < n4p; i += TPB2) {
        float4 v = p4[i];
        acc += (v.x + v.y) + (v.z + v.w);
    }
    for (int i = n4p * 4 + threadIdx.x; i < n; i += TPB2)
        acc += partial[i];

#pragma unroll
    for (int off = 32; off > 0; off >>= 1)
        acc += __shfl_down(acc, off, 64);

    __shared__ float s_partial[TPB2 / 64];
    const int lane = threadIdx.x & 63;
    const int wave = threadIdx.x >> 6;
    if (lane == 0) s_partial[wave] = acc;
    __syncthreads();

    if (threadIdx.x == 0) {
        float v = 0.0f;
#pragma unroll
        for (int w = 0; w < TPB2 / 64; ++w) v += s_partial[w];
        out[0] = v;
    }
}

extern "C" void kernel_launch(void* const* d_in, const int* in_sizes, int n_in,
                              void* d_out, int out_size, void* d_ws, size_t ws_size,
                              hipStream_t stream) {
    const float* pred = (const float*)d_in[0];
    const float* lab  = (const float*)d_in[1];
    float* out = (float*)d_out;
    float* partial = (float*)d_ws;

    long long n_elems = (long long)in_sizes[0];   // 25165824
    long long n4 = n_elems / 4;                   // 6291456

    // 4 float4s per thread per stream.
    int blocks = (int)((n4 + 4LL * TPB - 1) / (4LL * TPB));   // 6144
    if (blocks < 1) blocks = 1;

    loss_partial_kernel<<<blocks, TPB, 0, stream>>>(pred, lab, partial, n4, n_elems);
    reduce_partials_kernel<<<1, TPB2, 0, stream>>>(partial, out, blocks);
}